// Round 1
// baseline (555.328 us; speedup 1.0000x reference)
//
#include <hip/hip_runtime.h>
#include <hip/hip_bf16.h>

// Sizes (from setup_inputs): B=128, C=20000, F=64, K=32.
// Outputs flat-concat: fa [B*C*64] | ca [B*C] | mean [B] | pred [B], all f32.

#define EPS_DENOM 1e-10f

__device__ __forceinline__ float sigmoidf_fast(float x) {
    // 1 / (1 + e^{-x})
    return 1.0f / (1.0f + __expf(-x));
}

// Kernel 1: feature_activations + unnormalized case activations.
// Block = 256 threads = 16 pairs x 16 feature-groups (4 features each, float4).
__global__ void fa_ca_kernel(const float* __restrict__ q,
                             const float* __restrict__ cases,
                             const float* __restrict__ w_fa,
                             const float* __restrict__ b_fa,
                             const float* __restrict__ w_ca,
                             const float* __restrict__ b_ca,
                             float* __restrict__ fa_out,
                             float* __restrict__ ca_out,
                             int B, int C) {
    const int g = threadIdx.x & 15;   // feature group 0..15 (features g*4..g*4+3)
    const int p = threadIdx.x >> 4;   // pair slot 0..15
    const int c = blockIdx.x * 16 + p;
    const int b = blockIdx.y;
    if (c >= C) return;

    const int f4 = g * 4;
    const float4 qv = *reinterpret_cast<const float4*>(q     + (size_t)b * 64 + f4);
    const float4 cv = *reinterpret_cast<const float4*>(cases + (size_t)c * 64 + f4);
    const float4 wf = *reinterpret_cast<const float4*>(w_fa + f4);
    const float4 bf = *reinterpret_cast<const float4*>(b_fa + f4);
    const float4 wc = *reinterpret_cast<const float4*>(w_ca + f4);

    float d0 = qv.x - cv.x, d1 = qv.y - cv.y, d2 = qv.z - cv.z, d3 = qv.w - cv.w;
    // x = -d^2 * w_fa + b_fa ; sigmoid(x) = 1/(1+exp(d^2*w_fa - b_fa))
    float s0 = 1.0f / (1.0f + __expf(fmaf(d0 * d0, wf.x, -bf.x)));
    float s1 = 1.0f / (1.0f + __expf(fmaf(d1 * d1, wf.y, -bf.y)));
    float s2 = 1.0f / (1.0f + __expf(fmaf(d2 * d2, wf.z, -bf.z)));
    float s3 = 1.0f / (1.0f + __expf(fmaf(d3 * d3, wf.w, -bf.w)));

    float4 sv = make_float4(s0, s1, s2, s3);
    *reinterpret_cast<float4*>(fa_out + ((size_t)b * C + c) * 64 + f4) = sv;

    float dot = s0 * wc.x + s1 * wc.y + s2 * wc.z + s3 * wc.w;
    // reduce across the 16 lanes of this pair group (lanes share a wave)
    dot += __shfl_xor(dot, 1, 64);
    dot += __shfl_xor(dot, 2, 64);
    dot += __shfl_xor(dot, 4, 64);
    dot += __shfl_xor(dot, 8, 64);

    if (g == 0) {
        float cav = sigmoidf_fast(dot + b_ca[0]);
        ca_out[(size_t)b * C + c] = cav;  // unnormalized; kernel 2 rewrites
    }
}

// Kernel 2: per-row top-K selection, normalization, scalar outputs.
// One block per query row. Destructively selects from ca row (owned by this
// block), then rewrites the whole row as the final sparse/normalized output.
__global__ void topk_kernel(float* __restrict__ ca,
                            const float* __restrict__ labels,
                            float* __restrict__ out_mean,
                            float* __restrict__ out_pred,
                            int C, const int* __restrict__ kp) {
    __shared__ float sval[256];
    __shared__ int   sidx[256];
    __shared__ float selv[64];
    __shared__ int   seli[64];
    __shared__ float sdenom;

    int K = *kp;
    if (K > 64) K = 64;
    if (K < 1)  K = 1;

    const int b = blockIdx.x;
    const int t = threadIdx.x;
    float* row = ca + (size_t)b * C;

    for (int k = 0; k < K; ++k) {
        // thread-local argmax over strided slice; ties -> earliest index
        float bv = -1.0f;
        int   bi = C;
        for (int i = t; i < C; i += 256) {
            float v = row[i];
            if (v > bv) { bv = v; bi = i; }
        }
        sval[t] = bv; sidx[t] = bi;
        __syncthreads();
        for (int off = 128; off > 0; off >>= 1) {
            if (t < off) {
                float ov = sval[t + off]; int oi = sidx[t + off];
                if (ov > sval[t] || (ov == sval[t] && oi < sidx[t])) {
                    sval[t] = ov; sidx[t] = oi;
                }
            }
            __syncthreads();
        }
        if (t == 0) {
            selv[k] = sval[0];
            seli[k] = sidx[0];
            row[sidx[0]] = -1.0f;  // exclude from later passes
        }
        __syncthreads();
    }

    if (t == 0) {
        float s = 0.0f;
        for (int k = 0; k < K; ++k) s += selv[k];
        sdenom = s + EPS_DENOM;
    }
    __syncthreads();

    // rewrite row: zeros everywhere, then scatter normalized top-K
    for (int i = t; i < C; i += 256) row[i] = 0.0f;
    __syncthreads();
    const float denom = sdenom;
    if (t < K) row[seli[t]] = selv[t] / denom;

    if (t == 0) {
        float m = 0.0f, pr = 0.0f;
        for (int k = 0; k < K; ++k) {
            float lab = labels[seli[k]];
            m  += lab;
            pr += (selv[k] / denom) * lab;
        }
        out_mean[b] = m / (float)K;
        out_pred[b] = pr;
    }
}

extern "C" void kernel_launch(void* const* d_in, const int* in_sizes, int n_in,
                              void* d_out, int out_size, void* d_ws, size_t ws_size,
                              hipStream_t stream) {
    const float* q      = (const float*)d_in[0];
    const float* cases  = (const float*)d_in[1];
    const float* labels = (const float*)d_in[2];
    const float* w_fa   = (const float*)d_in[3];
    const float* b_fa   = (const float*)d_in[4];
    const float* w_ca   = (const float*)d_in[5];
    const float* b_ca   = (const float*)d_in[6];
    const int*   kp     = (const int*)d_in[7];

    const int F = in_sizes[3];          // 64
    const int B = in_sizes[0] / F;      // 128
    const int C = in_sizes[1] / F;      // 20000

    float* out      = (float*)d_out;
    const size_t FA = (size_t)B * C * F;
    float* fa_out   = out;
    float* ca_out   = out + FA;
    float* out_mean = ca_out + (size_t)B * C;
    float* out_pred = out_mean + B;

    dim3 g1((C + 15) / 16, B);
    fa_ca_kernel<<<g1, 256, 0, stream>>>(q, cases, w_fa, b_fa, w_ca, b_ca,
                                         fa_out, ca_out, B, C);
    topk_kernel<<<B, 256, 0, stream>>>(ca_out, labels, out_mean, out_pred, C, kp);
}

// Round 3
// 380.774 us; speedup vs baseline: 1.4584x; 1.4584x over previous
//
#include <hip/hip_runtime.h>
#include <hip/hip_bf16.h>

// B=128, C=20000, F=64, K=32.
// Outputs flat-concat: fa [B*C*64] | ca [B*C] | mean [B] | pred [B], all f32.

#define EPS_DENOM 1e-10f

typedef float floatx4 __attribute__((ext_vector_type(4)));

// ---------------------------------------------------------------------------
// Kernel 1: feature_activations (nontemporal streaming write) + unnormalized
// case activations. Block = 256 threads; 16 lanes per case (4 features each,
// float4); 4 cases per thread => 64 cases per block.
// ---------------------------------------------------------------------------
__global__ __launch_bounds__(256) void fa_ca_kernel(
    const float* __restrict__ q,
    const float* __restrict__ cases,
    const float* __restrict__ w_fa,
    const float* __restrict__ b_fa,
    const float* __restrict__ w_ca,
    const float* __restrict__ b_ca,
    float* __restrict__ fa_out,
    float* __restrict__ ca_out,
    int B, int C)
{
    const int g  = threadIdx.x & 15;   // feature group (features g*4 .. g*4+3)
    const int p  = threadIdx.x >> 4;   // case slot within block (0..15)
    const int b  = blockIdx.y;
    const int c0 = blockIdx.x * 64 + p;
    const int f4 = g * 4;

    const float4 qv = *reinterpret_cast<const float4*>(q    + (size_t)b * 64 + f4);
    const float4 wf = *reinterpret_cast<const float4*>(w_fa + f4);
    const float4 bf = *reinterpret_cast<const float4*>(b_fa + f4);
    const float4 wc = *reinterpret_cast<const float4*>(w_ca + f4);
    const float  bca = b_ca[0];

    #pragma unroll
    for (int j = 0; j < 4; ++j) {
        const int c = c0 + j * 16;
        if (c >= C) break;  // uniform within each 16-lane case group

        const float4 cv = *reinterpret_cast<const float4*>(cases + (size_t)c * 64 + f4);
        float d0 = qv.x - cv.x, d1 = qv.y - cv.y, d2 = qv.z - cv.z, d3 = qv.w - cv.w;
        // sigmoid(-d^2*w + b) = 1/(1+exp(d^2*w - b))
        float s0 = 1.0f / (1.0f + __expf(fmaf(d0 * d0, wf.x, -bf.x)));
        float s1 = 1.0f / (1.0f + __expf(fmaf(d1 * d1, wf.y, -bf.y)));
        float s2 = 1.0f / (1.0f + __expf(fmaf(d2 * d2, wf.z, -bf.z)));
        float s3 = 1.0f / (1.0f + __expf(fmaf(d3 * d3, wf.w, -bf.w)));

        floatx4 sv = { s0, s1, s2, s3 };
        __builtin_nontemporal_store(
            sv, reinterpret_cast<floatx4*>(fa_out + ((size_t)b * C + c) * 64 + f4));

        // same summation order as round 1 (keeps top-k boundary numerics)
        float dot = s0 * wc.x + s1 * wc.y + s2 * wc.z + s3 * wc.w;
        dot += __shfl_xor(dot, 1, 64);
        dot += __shfl_xor(dot, 2, 64);
        dot += __shfl_xor(dot, 4, 64);
        dot += __shfl_xor(dot, 8, 64);

        if (g == 0) {
            float cav = 1.0f / (1.0f + __expf(-(dot + bca)));
            ca_out[(size_t)b * C + c] = cav;  // raw; kernel 2 rewrites in place
        }
    }
}

// ---------------------------------------------------------------------------
// Kernel 2: per-row exact top-K via radix select (4x 8-bit passes), then
// normalize in place + scalar outputs. One block per query row.
// Values are sigmoid outputs (>= 0) so float bits sort as uint32.
// Tie-break: lowest index wins (matches jax.lax.top_k).
// ---------------------------------------------------------------------------
#define TPB2 256

__global__ __launch_bounds__(TPB2) void topk_kernel(
    float* __restrict__ ca,
    const float* __restrict__ labels,
    float* __restrict__ out_mean,
    float* __restrict__ out_pred,
    int C, const int* __restrict__ kp)
{
    __shared__ unsigned int hist[256];
    __shared__ unsigned int s_bsel;
    __shared__ int s_cum;
    __shared__ float s_red[TPB2];
    __shared__ float s_red2[TPB2];
    __shared__ int eq_buf[1024];
    __shared__ int eq_cnt;
    __shared__ int sel_eq[256];
    __shared__ int s_nsel;

    const int b = blockIdx.x;
    const int t = threadIdx.x;
    float* row = ca + (size_t)b * C;

    int K = *kp;
    if (K < 1) K = 1;
    if (K > 256) K = 256;

    // ---- radix select: exact K-th largest value (as uint key) ----
    unsigned int prefix = 0, pmask = 0;
    int remaining = K;

    for (int pass = 0; pass < 4; ++pass) {
        const int shift = 24 - 8 * pass;
        hist[t] = 0;
        __syncthreads();
        for (int i = t; i < C; i += TPB2) {
            unsigned int k = __float_as_uint(row[i]);
            if ((k & pmask) == prefix)
                atomicAdd(&hist[(k >> shift) & 255u], 1u);
        }
        __syncthreads();
        if (t == 0) {
            int cum = 0;
            int bsel = 0;
            for (int bin = 255; bin >= 0; --bin) {
                int h = (int)hist[bin];
                if (cum + h >= remaining) { bsel = bin; break; }
                cum += h;
            }
            s_bsel = (unsigned)bsel;
            s_cum = cum;
        }
        __syncthreads();
        prefix |= s_bsel << shift;
        pmask  |= 255u << shift;
        remaining -= s_cum;
        __syncthreads();
    }

    const float v32f = __uint_as_float(prefix);  // exact K-th largest value
    const int n_take = remaining;                // # ties (== v32f) to keep, >= 1

    // ---- Pass A: sum of strictly-greater values; collect tie indices ----
    if (t == 0) eq_cnt = 0;
    __syncthreads();
    float sum_gt = 0.0f;
    for (int i = t; i < C; i += TPB2) {
        float v = row[i];
        if (v > v32f) {
            sum_gt += v;
        } else if (v == v32f) {
            int slot = atomicAdd(&eq_cnt, 1);
            if (slot < 1024) eq_buf[slot] = i;
        }
    }
    s_red[t] = sum_gt;
    __syncthreads();
    for (int off = 128; off > 0; off >>= 1) {
        if (t < off) s_red[t] += s_red[t + off];
        __syncthreads();
    }
    const float denom_gt = s_red[0];
    const int n_eq = eq_cnt;

    // ---- choose which ties to keep (lowest indices) ----
    if (n_eq <= n_take) {
        if (t < n_eq) sel_eq[t] = eq_buf[t];
        if (t == 0) s_nsel = n_eq;
    } else if (n_eq <= 1024) {
        for (int e = t; e < n_eq; e += TPB2) {
            int idx = eq_buf[e];
            int rank = 0;
            for (int j = 0; j < n_eq; ++j) rank += (eq_buf[j] < idx) ? 1 : 0;
            if (rank < n_take) sel_eq[rank] = idx;
        }
        if (t == 0) s_nsel = n_take;
    } else {
        if (t == 0) {  // pathological tie flood: serial fallback
            int cnt = 0;
            for (int i = 0; i < C && cnt < n_take; ++i)
                if (row[i] == v32f) sel_eq[cnt++] = i;
            s_nsel = cnt;
        }
    }
    __syncthreads();
    const int nsel = s_nsel;
    const float denom = denom_gt + (float)nsel * v32f + EPS_DENOM;

    // ---- Pass B: rewrite row in place; accumulate label sums ----
    float lsum = 0.0f, psum = 0.0f;
    for (int i = t; i < C; i += TPB2) {
        float v = row[i];
        float outv = 0.0f;
        bool sel = (v > v32f);
        if (!sel && v == v32f) {
            for (int e = 0; e < nsel; ++e)
                if (sel_eq[e] == i) { sel = true; break; }
        }
        if (sel) {
            outv = v / denom;
            float lab = labels[i];
            lsum += lab;
            psum += outv * lab;
        }
        row[i] = outv;
    }
    s_red[t] = lsum;
    s_red2[t] = psum;
    __syncthreads();
    for (int off = 128; off > 0; off >>= 1) {
        if (t < off) { s_red[t] += s_red[t + off]; s_red2[t] += s_red2[t + off]; }
        __syncthreads();
    }
    if (t == 0) {
        out_mean[b] = s_red[0] / (float)K;
        out_pred[b] = s_red2[0];
    }
}

extern "C" void kernel_launch(void* const* d_in, const int* in_sizes, int n_in,
                              void* d_out, int out_size, void* d_ws, size_t ws_size,
                              hipStream_t stream) {
    const float* q      = (const float*)d_in[0];
    const float* cases  = (const float*)d_in[1];
    const float* labels = (const float*)d_in[2];
    const float* w_fa   = (const float*)d_in[3];
    const float* b_fa   = (const float*)d_in[4];
    const float* w_ca   = (const float*)d_in[5];
    const float* b_ca   = (const float*)d_in[6];
    const int*   kp     = (const int*)d_in[7];

    const int F = in_sizes[3];          // 64
    const int B = in_sizes[0] / F;      // 128
    const int C = in_sizes[1] / F;      // 20000

    float* out      = (float*)d_out;
    const size_t FA = (size_t)B * C * F;
    float* fa_out   = out;
    float* ca_out   = out + FA;
    float* out_mean = ca_out + (size_t)B * C;
    float* out_pred = out_mean + B;

    dim3 g1((C + 63) / 64, B);
    fa_ca_kernel<<<g1, 256, 0, stream>>>(q, cases, w_fa, b_fa, w_ca, b_ca,
                                         fa_out, ca_out, B, C);
    topk_kernel<<<B, TPB2, 0, stream>>>(ca_out, labels, out_mean, out_pred, C, kp);
}